// Round 1
// baseline (437.468 us; speedup 1.0000x reference)
//
#include <hip/hip_runtime.h>

// SparseInputLayer: inputs [B, ND*(1+NS)] fp32.
//  - cols [0,64): channel indices (float-encoded ints in [0,384))
//  - cols [64, 64+64*121): data rows x[b][j][s]
// out[b][c][s] = sum_{j: idx[b][j]==c} x[b][j][s], shape [2048,384,121,1] fp32.
//
// Strategy: one block per batch. Build per-channel 64-bit "which j maps here"
// bitmask in LDS (scatter -> gather inversion), then stream the full output
// row [384*121] with one coalesced write per element (fuses zero-fill with
// the scatter-add; no global atomics, no memset pass).

#define BATCH 2048
#define N_DENSE 64
#define N_SAMPLES 121
#define N_CHANNELS 384
#define ROW_IN (N_DENSE * (1 + N_SAMPLES)) // 7808 floats per input row
#define ROW_OUT (N_CHANNELS * N_SAMPLES)   // 46464 floats per output row
#define BLOCK 256

__global__ __launch_bounds__(BLOCK) void sparse_scatter_kernel(
    const float* __restrict__ in, float* __restrict__ out) {
  __shared__ unsigned long long mask[N_CHANNELS];

  const int b = blockIdx.x;
  const int tid = threadIdx.x;

  // init per-channel membership masks
  for (int c = tid; c < N_CHANNELS; c += BLOCK) mask[c] = 0ull;
  __syncthreads();

  // threads 0..63 each own one dense slot j; set bit j in its channel's mask
  if (tid < N_DENSE) {
    const int c = (int)in[(size_t)b * ROW_IN + tid];
    atomicOr(&mask[c], 1ull << tid);
  }
  __syncthreads();

  const float* __restrict__ x = in + (size_t)b * ROW_IN + N_DENSE; // [64][121]
  float* __restrict__ o = out + (size_t)b * ROW_OUT;               // [384][121]

  // stream the output row: element e -> (c = e/121, s = e%121)
  for (int e = tid; e < ROW_OUT; e += BLOCK) {
    const int c = e / N_SAMPLES;
    const int s = e - c * N_SAMPLES;
    unsigned long long m = mask[c]; // LDS broadcast (same addr across the c-group)
    float sum = 0.0f;
    while (m) {
      const int j = __builtin_ctzll(m);
      m &= m - 1;
      sum += x[j * N_SAMPLES + s]; // per-batch x slab is 31 KB -> L1 resident
    }
    o[e] = sum; // exactly-once, fully coalesced store
  }
}

extern "C" void kernel_launch(void* const* d_in, const int* in_sizes, int n_in,
                              void* d_out, int out_size, void* d_ws, size_t ws_size,
                              hipStream_t stream) {
  const float* in = (const float*)d_in[0];
  float* out = (float*)d_out;
  sparse_scatter_kernel<<<BATCH, BLOCK, 0, stream>>>(in, out);
}